// Round 14
// baseline (392.753 us; speedup 1.0000x reference)
//
#include <hip/hip_runtime.h>
#include <hip/hip_bf16.h>

// Joiner: out[m, v] = tanh(enc[b_m, t_m, :] + dec[b_m, u_m, :]) @ W[v, :]^T + bias[v]
// M ~ 295k rows, K = 512, V = 500 (padded to 512).
// r14: request-byte reduction via 2D (t,u) tiling. The ragged index set is a
// per-batch cross product T_b x U_b; an 8x8 tile block reads 8 enc + 8 dec rows
// (32KB) for 64 output rows instead of 64x4KB=256KB -> gather 1.18GB -> ~0.15GB.
// Prep kernels build a per-b table {m_start, T_b, U_b, tile_prefix} in d_ws.
// GEMM + epilogue frozen from r13 (proven); store row = m_start + t*U_b + u.

typedef __attribute__((ext_vector_type(8))) short short8;   // 8 bf16
typedef __attribute__((ext_vector_type(4))) float f32x4;    // MFMA acc / NT store

#define TDIM 512
#define UDIM 64
#define DDIM 512

__device__ __forceinline__ unsigned short f2bf(float v) {
    unsigned int u = __float_as_uint(v);
    u += 0x7fffu + ((u >> 16) & 1u);
    return (unsigned short)(u >> 16);
}

// One v_cvt_pk_bf16_f32: packs (a,b) -> bf16x2 with RNE.
__device__ __forceinline__ unsigned pack_bf16x2(float a, float b) {
    __hip_bfloat162 h = __float22bfloat162_rn(make_float2(a, b));
    unsigned u;
    __builtin_memcpy(&u, &h, 4);
    return u;
}

__device__ __forceinline__ float bf_lo(unsigned u) { return __uint_as_float(u << 16); }
__device__ __forceinline__ float bf_hi(unsigned u) { return __uint_as_float(u & 0xffff0000u); }

// Symmetric fast tanh: t = e^{2x}; (t-1)/(t+1). Safe for |x| < 44.
__device__ __forceinline__ float tanh_fast(float x) {
    float t = __builtin_amdgcn_exp2f(x * 2.8853900817779268f);
    return (t - 1.0f) * __builtin_amdgcn_rcpf(t + 1.0f);
}

// W (500x512 f32) -> 512x512 bf16 (rows 500..511 zero) in workspace.
__global__ void prep_w_kernel(const float* __restrict__ W, unsigned short* __restrict__ Wbf) {
    const int i = blockIdx.x * blockDim.x + threadIdx.x;
    const int base = i << 2;
    const int n = base >> 9;
    const int k = base & 511;
    float4 v = make_float4(0.f, 0.f, 0.f, 0.f);
    if (n < 500) v = *reinterpret_cast<const float4*>(W + ((size_t)n << 9) + k);
    uint2 p;
    p.x = pack_bf16x2(v.x, v.y);
    p.y = pack_bf16x2(v.z, v.w);
    *reinterpret_cast<uint2*>(Wbf + base) = p;
}

// ---- per-batch table in d_ws: tbl[b*4] = {m_start, T_b, U_b, tile_prefix}, tbl[4N]=total ----
__global__ void prep_table_init(int* tbl, int N) {
    const int i = threadIdx.x;
    if (i < N) {
        tbl[i * 4 + 0] = 0x7fffffff;
        tbl[i * 4 + 1] = 0;
        tbl[i * 4 + 2] = 0;
        tbl[i * 4 + 3] = 0;
    }
}

__global__ void prep_table_scan(const int* __restrict__ b_idx, const int* __restrict__ t_idx,
                                const int* __restrict__ u_idx, int* tbl, int M, int N) {
    __shared__ int sMin[64], sTb[64], sUb[64];
    const int tid = threadIdx.x;
    if (tid < 64) { sMin[tid] = 0x7fffffff; sTb[tid] = 0; sUb[tid] = 0; }
    __syncthreads();
    const int stride = gridDim.x * blockDim.x;
    for (int m = blockIdx.x * blockDim.x + tid; m < M; m += stride) {
        const int b = b_idx[m];
        atomicMin(&sMin[b], m);
        atomicMax(&sTb[b], t_idx[m] + 1);
        atomicMax(&sUb[b], u_idx[m] + 1);
    }
    __syncthreads();
    if (tid < N && sTb[tid] > 0) {
        atomicMin(&tbl[tid * 4 + 0], sMin[tid]);
        atomicMax(&tbl[tid * 4 + 1], sTb[tid]);
        atomicMax(&tbl[tid * 4 + 2], sUb[tid]);
    }
}

__global__ void prep_table_fin(int* tbl, int N) {
    if (blockIdx.x == 0 && threadIdx.x == 0) {
        int pref = 0;
        for (int b = 0; b < N; ++b) {
            const int Tb = tbl[b * 4 + 1], Ub = tbl[b * 4 + 2];
            tbl[b * 4 + 3] = pref;
            pref += ((Tb + 7) >> 3) * ((Ub + 7) >> 3);
        }
        tbl[4 * N] = pref;
    }
}

// ---- main kernel: block = 8x8 (t,u) tile of one batch; 512 thr / 8 waves ----
// LDS 81920B = exactly 2 blocks/CU: Abuf [0,64K) bf16 swizzled;
// encS [64K,+8K) bf16; decS [72K,+8K) bf16; Obuf [0,65792) aliases (dead regions).
__global__ __launch_bounds__(512, 4)
void joiner_tile_kernel(const float* __restrict__ enc, const float* __restrict__ dec,
                        const float* __restrict__ bias,
                        const unsigned short* __restrict__ Wbf,
                        const int* __restrict__ tbl,
                        float* __restrict__ out, int N)
{
    __shared__ unsigned char LDS[81920];

    const int tid  = threadIdx.x;
    const int lane = tid & 63;
    const int bid  = blockIdx.x;

    const int total = tbl[4 * N];
    if (bid >= total) return;

    int b = 0;
    for (int i = N - 1; i > 0; --i) { if (bid >= tbl[i * 4 + 3]) { b = i; break; } }
    const int m_start = tbl[b * 4 + 0];
    const int Tb      = tbl[b * 4 + 1];
    const int Ub      = tbl[b * 4 + 2];
    const int local   = bid - tbl[b * 4 + 3];
    const int nUu = (Ub + 7) >> 3;
    const int ti  = local / nUu;
    const int uj  = local - ti * nUu;
    const int t0  = ti << 3;
    const int u0  = uj << 3;

    // ------- Stage 8 enc + 8 dec rows -> LDS bf16 (the dedup: 32KB not 256KB) -------
    {
        const int row = tid >> 5;        // 0..15 (0..7 enc, 8..15 dec)
        const int c   = tid & 31;
        const float* src;
        int lbase;
        if (row < 8) {
            const int t = min(t0 + row, Tb - 1);
            src = enc + ((size_t)b * TDIM + t) * DDIM;
            lbase = 65536 + row * 1024;
        } else {
            const int u = min(u0 + row - 8, Ub - 1);
            src = dec + ((size_t)b * UDIM + u) * DDIM;
            lbase = 73728 + (row - 8) * 1024;
        }
        #pragma unroll
        for (int q = 0; q < 4; ++q) {
            const int cc = q * 32 + c;   // float4 chunk 0..127; lanes contiguous
            const float4 v = *reinterpret_cast<const float4*>(src + cc * 4);
            uint2 pk;
            pk.x = pack_bf16x2(v.x, v.y);
            pk.y = pack_bf16x2(v.z, v.w);
            *reinterpret_cast<uint2*>(&LDS[lbase + cc * 8]) = pk;
        }
    }
    __syncthreads();

    // ------- Phase 1: activations LDS->LDS; Abuf row r = (i=r>>3)*8 + (j=r&7) -------
    {
        const int rr = tid >> 7;         // 0..3
        const int kq = tid & 127;        // 8B chunk in 512-wide row
        #pragma unroll
        for (int p = 0; p < 16; ++p) {
            const int r = p * 4 + rr;
            const int i = r >> 3, j = r & 7;
            const uint2 ev = *reinterpret_cast<const uint2*>(&LDS[65536 + i * 1024 + kq * 8]);
            const uint2 dv = *reinterpret_cast<const uint2*>(&LDS[73728 + j * 1024 + kq * 8]);
            const float x0 = bf_lo(ev.x) + bf_lo(dv.x);
            const float x1 = bf_hi(ev.x) + bf_hi(dv.x);
            const float x2 = bf_lo(ev.y) + bf_lo(dv.y);
            const float x3 = bf_hi(ev.y) + bf_hi(dv.y);
            uint2 pk;
            pk.x = pack_bf16x2(tanh_fast(x0), tanh_fast(x1));
            pk.y = pack_bf16x2(tanh_fast(x2), tanh_fast(x3));
            const int byteoff = (r * 1024 + kq * 8) ^ ((r & 7) << 4);
            *reinterpret_cast<uint2*>(&LDS[byteoff]) = pk;
        }
    }

    // ------- Phase 2: MFMA GEMM (frozen from r13), depth-2 B prefetch -------
    const int wv   = tid >> 6;           // wave 0..7 -> cols [wv*64, +64)
    const int l15  = lane & 15;
    const int lk   = lane >> 4;
    const int n_wave = wv << 6;
    const int a_swz  = (l15 & 7) << 4;

    f32x4 acc[4][4];
    #pragma unroll
    for (int mf = 0; mf < 4; ++mf)
        #pragma unroll
        for (int nf = 0; nf < 4; ++nf)
            acc[mf][nf] = (f32x4)(0.0f);

    const unsigned short* wp = Wbf + (((size_t)(n_wave + l15)) << 9) + (lk << 3);
    auto loadB = [&](int ks, int nf) -> short8 {
        return *reinterpret_cast<const short8*>(wp + nf * 8192 + ks * 32);
    };

    short8 Bf[2][4];
    #pragma unroll
    for (int nf = 0; nf < 4; ++nf) Bf[0][nf] = loadB(0, nf);
    #pragma unroll
    for (int nf = 0; nf < 4; ++nf) Bf[1][nf] = loadB(1, nf);

    __syncthreads();                     // Abuf ready

    #pragma unroll
    for (int ks = 0; ks < 16; ++ks) {
        short8 a[4];
        #pragma unroll
        for (int mf = 0; mf < 4; ++mf) {
            const int addr = (((mf * 16 + l15) << 10) + ks * 64 + lk * 16) ^ a_swz;
            a[mf] = *reinterpret_cast<const short8*>(&LDS[addr]);
        }
        __builtin_amdgcn_s_setprio(1);
        #pragma unroll
        for (int mf = 0; mf < 4; ++mf)
            #pragma unroll
            for (int nf = 0; nf < 4; ++nf)
                acc[mf][nf] = __builtin_amdgcn_mfma_f32_16x16x32_bf16(a[mf], Bf[ks & 1][nf], acc[mf][nf], 0, 0, 0);
        __builtin_amdgcn_s_setprio(0);
        if (ks < 14) {
            #pragma unroll
            for (int nf = 0; nf < 4; ++nf) Bf[ks & 1][nf] = loadB(ks + 2, nf);
        }
    }

    // ------- Epilogue: bias + Obuf transpose + NT stores (row = m_start + t*Ub + u) -------
    #pragma unroll
    for (int nf = 0; nf < 4; ++nf) {
        const int col = n_wave + nf * 16 + l15;
        const float bv = (col < 500) ? bias[col] : 0.0f;
        #pragma unroll
        for (int mf = 0; mf < 4; ++mf)
            #pragma unroll
            for (int j = 0; j < 4; ++j)
                acc[mf][nf][j] += bv;
    }

    float* Obuf = reinterpret_cast<float*>(LDS);   // [64][257] f32
    #pragma unroll
    for (int h = 0; h < 2; ++h) {
        __syncthreads();                 // protects Abuf/Obuf aliasing
        if ((wv >> 2) == h) {
            const int lcol = (wv & 3) << 6;
            #pragma unroll
            for (int mf = 0; mf < 4; ++mf)
                #pragma unroll
                for (int nf = 0; nf < 4; ++nf)
                    #pragma unroll
                    for (int j = 0; j < 4; ++j) {
                        const int r = mf * 16 + lk * 4 + j;
                        Obuf[r * 257 + lcol + nf * 16 + l15] = acc[mf][nf][j];
                    }
        }
        __syncthreads();
        #pragma unroll
        for (int i = 0; i < 8; ++i) {
            const int linear = i * 512 + tid;
            const int r  = linear >> 6;
            const int c4 = linear & 63;
            const int ii = r >> 3, jj = r & 7;
            const int t = t0 + ii, u = u0 + jj;
            const int col = (h << 8) + (c4 << 2);
            if (t < Tb && u < Ub && col < 500) {
                const int row_g = m_start + t * Ub + u;
                const f32x4 v = *reinterpret_cast<const f32x4*>(&Obuf[r * 257 + (c4 << 2)]);
                __builtin_nontemporal_store(v, reinterpret_cast<f32x4*>(&out[(size_t)row_g * 500 + col]));
            }
        }
    }
}

// ---- fallback (r13, f32 W path, flat row mapping) if d_ws is too small ----
__global__ __launch_bounds__(512, 4)
void joiner_fallback_kernel(const float* __restrict__ enc, const float* __restrict__ dec,
                            const float* __restrict__ W, const float* __restrict__ bias,
                            const int* __restrict__ b_idx, const int* __restrict__ t_idx,
                            const int* __restrict__ u_idx,
                            float* __restrict__ out, int M)
{
    __shared__ unsigned char Abuf[65792];
    const int tid  = threadIdx.x;
    const int lane = tid & 63;
    const int m0   = blockIdx.x * 64;

    const int rr = tid >> 7;
    int eoff_l, doff_l;
    {
        const int rc = min(m0 + ((lane & 15) << 2) + rr, M - 1);
        const int bi = b_idx[rc];
        eoff_l = ((bi << 9) + t_idx[rc]) << 9;
        doff_l = ((bi << 6) + u_idx[rc]) << 9;
    }
    {
        const int kq  = tid & 127;
        const int kq4 = kq << 2;
        float4 es[6], dsv[6];
        #pragma unroll
        for (int i = 0; i < 6; ++i) {
            es[i]  = *reinterpret_cast<const float4*>(enc + __builtin_amdgcn_readlane(eoff_l, i) + kq4);
            dsv[i] = *reinterpret_cast<const float4*>(dec + __builtin_amdgcn_readlane(doff_l, i) + kq4);
        }
        #pragma unroll
        for (int p = 0; p < 16; ++p) {
            const int s = p % 6;
            const float4 e = es[s];
            const float4 d = dsv[s];
            if (p + 6 < 16) {
                es[s]  = *reinterpret_cast<const float4*>(enc + __builtin_amdgcn_readlane(eoff_l, p + 6) + kq4);
                dsv[s] = *reinterpret_cast<const float4*>(dec + __builtin_amdgcn_readlane(doff_l, p + 6) + kq4);
            }
            uint2 packed;
            packed.x = pack_bf16x2(tanh_fast(e.x + d.x), tanh_fast(e.y + d.y));
            packed.y = pack_bf16x2(tanh_fast(e.z + d.z), tanh_fast(e.w + d.w));
            const int r = p * 4 + rr;
            const int byteoff = (r * 1024 + kq * 8) ^ ((r & 7) << 4);
            *reinterpret_cast<uint2*>(&Abuf[byteoff]) = packed;
        }
    }
    const int wv   = tid >> 6;
    const int l15  = lane & 15;
    const int lk   = lane >> 4;
    const int n_wave = wv << 6;
    const int a_swz  = (l15 & 7) << 4;

    f32x4 acc[4][4];
    #pragma unroll
    for (int mf = 0; mf < 4; ++mf)
        #pragma unroll
        for (int nf = 0; nf < 4; ++nf)
            acc[mf][nf] = (f32x4)(0.0f);

    const float* wpf = W + (((size_t)(n_wave + l15)) << 9) + (lk << 3);
    const int colbase = n_wave + l15;
    auto loadB = [&](int ks, int nf) -> short8 {
        short8 b;
        float4 w0 = make_float4(0,0,0,0), w1 = make_float4(0,0,0,0);
        if (colbase + nf * 16 < 500) {
            const float4* q = reinterpret_cast<const float4*>(wpf + nf * 8192 + ks * 32);
            w0 = q[0]; w1 = q[1];
        }
        b[0] = (short)f2bf(w0.x); b[1] = (short)f2bf(w0.y);
        b[2] = (short)f2bf(w0.z); b[3] = (short)f2bf(w0.w);
        b[4] = (short)f2bf(w1.x); b[5] = (short)f2bf(w1.y);
        b[6] = (short)f2bf(w1.z); b[7] = (short)f2bf(w1.w);
        return b;
    };

    short8 Bf[2][4];
    #pragma unroll
    for (int nf = 0; nf < 4; ++nf) Bf[0][nf] = loadB(0, nf);
    #pragma unroll
    for (int nf = 0; nf < 4; ++nf) Bf[1][nf] = loadB(1, nf);
    __syncthreads();
    #pragma unroll
    for (int ks = 0; ks < 16; ++ks) {
        short8 a[4];
        #pragma unroll
        for (int mf = 0; mf < 4; ++mf) {
            const int addr = (((mf * 16 + l15) << 10) + ks * 64 + lk * 16) ^ a_swz;
            a[mf] = *reinterpret_cast<const short8*>(&Abuf[addr]);
        }
        #pragma unroll
        for (int mf = 0; mf < 4; ++mf)
            #pragma unroll
            for (int nf = 0; nf < 4; ++nf)
                acc[mf][nf] = __builtin_amdgcn_mfma_f32_16x16x32_bf16(a[mf], Bf[ks & 1][nf], acc[mf][nf], 0, 0, 0);
        if (ks < 14) {
            #pragma unroll
            for (int nf = 0; nf < 4; ++nf) Bf[ks & 1][nf] = loadB(ks + 2, nf);
        }
    }
    #pragma unroll
    for (int nf = 0; nf < 4; ++nf) {
        const int col = n_wave + nf * 16 + l15;
        const float bv = (col < 500) ? bias[col] : 0.0f;
        #pragma unroll
        for (int mf = 0; mf < 4; ++mf)
            #pragma unroll
            for (int j = 0; j < 4; ++j)
                acc[mf][nf][j] += bv;
    }
    float* Obuf = reinterpret_cast<float*>(Abuf);
    #pragma unroll
    for (int h = 0; h < 2; ++h) {
        __syncthreads();
        if ((wv >> 2) == h) {
            const int lcol = (wv & 3) << 6;
            #pragma unroll
            for (int mf = 0; mf < 4; ++mf)
                #pragma unroll
                for (int nf = 0; nf < 4; ++nf)
                    #pragma unroll
                    for (int j = 0; j < 4; ++j) {
                        const int r = mf * 16 + lk * 4 + j;
                        Obuf[r * 257 + lcol + nf * 16 + l15] = acc[mf][nf][j];
                    }
        }
        __syncthreads();
        #pragma unroll
        for (int i = 0; i < 8; ++i) {
            const int linear = i * 512 + tid;
            const int r  = linear >> 6;
            const int c4 = linear & 63;
            const int row = m0 + r;
            const int col = (h << 8) + (c4 << 2);
            if (row < M && col < 500) {
                const f32x4 v = *reinterpret_cast<const f32x4*>(&Obuf[r * 257 + (c4 << 2)]);
                __builtin_nontemporal_store(v, reinterpret_cast<f32x4*>(&out[(size_t)row * 500 + col]));
            }
        }
    }
}

extern "C" void kernel_launch(void* const* d_in, const int* in_sizes, int n_in,
                              void* d_out, int out_size, void* d_ws, size_t ws_size,
                              hipStream_t stream) {
    const float* enc  = (const float*)d_in[0];
    const float* dec  = (const float*)d_in[1];
    const float* W    = (const float*)d_in[2];
    const float* bias = (const float*)d_in[3];
    const int* bi = (const int*)d_in[4];
    const int* ti = (const int*)d_in[5];
    const int* ui = (const int*)d_in[6];
    float* out = (float*)d_out;

    const int M = in_sizes[4];
    const int N = in_sizes[0] / (TDIM * DDIM);

    const size_t wbf_bytes = (size_t)512 * 512 * 2;
    const size_t tbl_off   = wbf_bytes;
    const size_t need      = tbl_off + (size_t)(4 * N + 1) * 4;

    if (ws_size >= need && N <= 64) {
        unsigned short* Wbf = (unsigned short*)d_ws;
        int* tbl = (int*)((char*)d_ws + tbl_off);
        prep_w_kernel<<<256, 256, 0, stream>>>(W, Wbf);
        prep_table_init<<<1, 64, 0, stream>>>(tbl, N);
        prep_table_scan<<<64, 256, 0, stream>>>(bi, ti, ui, tbl, M, N);
        prep_table_fin<<<1, 1, 0, stream>>>(tbl, N);
        const int grid = N * ((TDIM + 7) / 8) * ((UDIM + 7) / 8);   // upper bound; extras exit
        joiner_tile_kernel<<<grid, 512, 0, stream>>>(enc, dec, bias, Wbf, tbl, out, N);
    } else {
        const int grid = (M + 63) / 64;
        joiner_fallback_kernel<<<grid, 512, 0, stream>>>(enc, dec, W, bias, bi, ti, ui, out, M);
    }
}